// Round 6
// baseline (219.346 us; speedup 1.0000x reference)
//
#include <hip/hip_runtime.h>

// LearnedSegmentEncoder on MI355X — per-wave global_load_lds pipeline, depth-3
// counted vmcnt, no loop barriers. B=8, C=128, P=65536, D=64, S=32.
// Identity: pooled = conv2_w @ mean_seg(relu(conv1_w@x+b1)) + b2, so only
// conv1 runs per-pixel (bf16 MFMA GEMM, M=BP, N=64, K=128).
// Key trick: global_load_lds source addr is PER-LANE -> one 4-byte gather
// instr deposits a [4c x 16px] f32 sub-tile in MFMA A-fragment order.
// 48 loads (12 KB) per wave stay in flight continuously (compiler cannot
// cap this: zero VGPRs, literal vmcnt waits, no vmem results in the loop).

#define B_ 8
#define C_ 128
#define P_ 65536
#define D_ 64
#define S_ 32
#define WPB 4                   // waves per block
#define PXW 256                 // pixels per wave (16 tiles of 16)
#define TMB (WPB * PXW)         // 1024 pixels per block

typedef short bf16x8 __attribute__((ext_vector_type(8)));
typedef float f32x4  __attribute__((ext_vector_type(4)));

__device__ __forceinline__ short f2bf(float f) {
  union { float f; unsigned u; } v; v.f = f;
  unsigned r = v.u + 0x7fffu + ((v.u >> 16) & 1u);   // RNE
  return (short)(r >> 16);
}

__global__ __launch_bounds__(256) void w1_to_bf16(const float* __restrict__ w1,
                                                  short* __restrict__ wbf) {
  int i = blockIdx.x * 256 + threadIdx.x;
  if (i < C_ * D_) wbf[i] = f2bf(w1[i]);
}

__device__ __forceinline__ void gload4(const float* g, const float* l) {
  __builtin_amdgcn_global_load_lds(
      (const __attribute__((address_space(1))) float*)g,
      (__attribute__((address_space(3))) float*)l, 4, 0, 0);
}

// Grid (P/TMB, B) = (64, 8) = 512 blocks -> exactly 2/CU, all resident.
__global__ __launch_bounds__(256, 2) void proj_mfma(
    const int* __restrict__ labels, const float* __restrict__ feat,
    const short* __restrict__ wbf, const float* __restrict__ b1,
    float* __restrict__ gsum, int* __restrict__ gcnt)
{
  // per-wave private pipeline: 4 slots x (64c x 16px) f32 = 4 x 4 KB
  __shared__ __align__(16) float xpipe[WPB][4][64 * 16];   // 64 KB
  __shared__ int   lab_lds[TMB];                           // 4 KB
  __shared__ float s_acc[S_][68];                          // 8.5 KB
  __shared__ int   s_cnt[S_];
  __shared__ float s_b1[D_];

  const int tid  = threadIdx.x;
  const int wave = tid >> 6, l = tid & 63, m = l & 15, g = l >> 4;
  const int b    = blockIdx.y;
  const int px0  = blockIdx.x * TMB;

  // ---- prologue staging (the only barriers in the kernel) ----
  *(int4*)&lab_lds[tid * 4] = *(const int4*)&labels[(size_t)b * P_ + px0 + tid * 4];
  for (int i = tid; i < S_ * 68; i += 256) ((float*)s_acc)[i] = 0.f;
  if (tid < S_) s_cnt[tid] = 0;
  if (tid < D_) s_b1[tid] = b1[tid];
  // stage W1(bf16) into xpipe[0] region (16 KB), read fragments, then reuse
  {
    short* wst = (short*)&xpipe[0][0][0];
    for (int i = tid; i < C_ * D_ / 8; i += 256)
      ((bf16x8*)wst)[i] = ((const bf16x8*)wbf)[i];
  }
  __syncthreads();
  bf16x8 bfr[4][4];
  #pragma unroll
  for (int nt = 0; nt < 4; ++nt)
    #pragma unroll
    for (int ks = 0; ks < 4; ++ks)
      bfr[nt][ks] = *(const bf16x8*)&((const short*)&xpipe[0][0][0])
                        [(nt * 16 + m) * C_ + ks * 32 + g * 8];
  float b1v[4];
  #pragma unroll
  for (int nt = 0; nt < 4; ++nt) b1v[nt] = s_b1[nt * 16 + m];
  __syncthreads();   // wstage fully read -> xpipe reusable

  // per-lane global base: channel g, pixel m of this wave's range
  const float* xg = feat + (size_t)b * C_ * P_ + (size_t)g * P_
                  + px0 + wave * PXW + m;

  // chunk c (0..31): tile t=c>>1 (16 px), K-half h=c&1 (channels h*64..h*64+63)
  // instr i (0..15): channels h*64 + 4i + g, pixel t*16 + m
#define STAGE(c_) do {                                                        \
    const int t_ = (c_) >> 1, h_ = (c_) & 1;                                  \
    const float* gb_ = xg + (size_t)(h_ * 64) * P_ + t_ * 16;                 \
    const float* lb_ = &xpipe[wave][(c_) & 3][0];                             \
    _Pragma("unroll") for (int i = 0; i < 16; ++i)                            \
      gload4(gb_ + (size_t)(i * 4) * P_, lb_ + i * 64);                       \
  } while (0)

#define WAITV(n_) asm volatile("s_waitcnt vmcnt(" #n_ ")" ::: "memory");      \
                  __builtin_amdgcn_sched_barrier(0)

#define CONSUME0(t_) do {                                                     \
    const float* cb_ = &xpipe[wave][(2 * (t_)) & 3][0];                       \
    _Pragma("unroll") for (int kk = 0; kk < 2; ++kk) {                        \
      bf16x8 af;                                                              \
      _Pragma("unroll") for (int j = 0; j < 8; ++j)                           \
        af[j] = f2bf(cb_[(kk * 32 + g * 8 + j) * 16 + m]);                    \
      _Pragma("unroll") for (int nt = 0; nt < 4; ++nt)                        \
        acc[nt] = __builtin_amdgcn_mfma_f32_16x16x32_bf16(af, bfr[nt][kk],    \
                                                          acc[nt], 0, 0, 0); \
    }                                                                         \
  } while (0)

#define CONSUME1(t_) do {                                                     \
    const float* cb_ = &xpipe[wave][(2 * (t_) + 1) & 3][0];                   \
    _Pragma("unroll") for (int kk = 0; kk < 2; ++kk) {                        \
      bf16x8 af;                                                              \
      _Pragma("unroll") for (int j = 0; j < 8; ++j)                           \
        af[j] = f2bf(cb_[(kk * 32 + g * 8 + j) * 16 + m]);                    \
      _Pragma("unroll") for (int nt = 0; nt < 4; ++nt)                        \
        acc[nt] = __builtin_amdgcn_mfma_f32_16x16x32_bf16(af, bfr[nt][2 + kk],\
                                                          acc[nt], 0, 0, 0); \
    }                                                                         \
    const int4 lv = *(const int4*)&lab_lds[wave * PXW + (t_) * 16 + g * 4];   \
    _Pragma("unroll") for (int nt = 0; nt < 4; ++nt)                          \
      _Pragma("unroll") for (int r = 0; r < 4; ++r) {                         \
        const int lab = ((r & 2) ? ((r & 1) ? lv.w : lv.z)                    \
                                 : ((r & 1) ? lv.y : lv.x)) & (S_ - 1);       \
        atomicAdd(&s_acc[lab][nt * 16 + m],                                   \
                  fmaxf(acc[nt][r] + b1v[nt], 0.f));                          \
      }                                                                       \
    if (m < 4) {                                                              \
      const int lab = ((m & 2) ? ((m & 1) ? lv.w : lv.z)                      \
                               : ((m & 1) ? lv.y : lv.x)) & (S_ - 1);         \
      atomicAdd(&s_cnt[lab], 1);                                              \
    }                                                                         \
  } while (0)

  f32x4 acc[4];
  STAGE(0); STAGE(1); STAGE(2);               // 48 outstanding (max, <=63)

  for (int t2 = 0; t2 < 15; ++t2) {
    WAITV(32);                                 // chunk 2*t2 landed
    STAGE(2 * t2 + 3);
    #pragma unroll
    for (int nt = 0; nt < 4; ++nt) acc[nt] = (f32x4){0.f, 0.f, 0.f, 0.f};
    CONSUME0(t2);
    WAITV(32);                                 // chunk 2*t2+1 landed
    if (t2 < 14) STAGE(2 * t2 + 4);
    CONSUME1(t2);
  }
  WAITV(16);
  #pragma unroll
  for (int nt = 0; nt < 4; ++nt) acc[nt] = (f32x4){0.f, 0.f, 0.f, 0.f};
  CONSUME0(15);
  WAITV(0);
  CONSUME1(15);

#undef STAGE
#undef WAITV
#undef CONSUME0
#undef CONSUME1

  __syncthreads();
  for (int i = tid; i < S_ * D_; i += 256)
    atomicAdd(&gsum[(size_t)b * S_ * D_ + i], s_acc[i >> 6][i & 63]);
  if (tid < S_) atomicAdd(&gcnt[b * S_ + tid], s_cnt[tid]);
}

// Grid (S, B), 64 lanes: all (b,s) blocks independent; ballot-based rank.
__global__ __launch_bounds__(64) void seg_finalize2(
    const float* __restrict__ gsum, const int* __restrict__ gcnt,
    const float* __restrict__ w2, const float* __restrict__ b2,
    const float* __restrict__ emb, const float* __restrict__ wo,
    const float* __restrict__ bo, float* __restrict__ out)
{
  const int s = blockIdx.x, b = blockIdx.y, o = threadIdx.x;
  const int co = (o < S_) ? gcnt[b * S_ + o] : 0;
  const unsigned long long mask = __ballot(co > 0);
  const int cnt = gcnt[b * S_ + s];
  if (cnt <= 0) return;                               // uniform exit
  const int rank = __popcll(mask & ((1ull << s) - 1ull));

  __shared__ float s_mean[D_], s_pool[D_];
  s_mean[o] = gsum[((size_t)b * S_ + s) * D_ + o] * (1.f / (float)cnt);
  __syncthreads();
  float pooled = b2[o];
  #pragma unroll
  for (int d = 0; d < D_; ++d) pooled += w2[o * D_ + d] * s_mean[d];
  s_pool[o] = pooled;
  __syncthreads();
  float r = bo[o];
  #pragma unroll
  for (int e = 0; e < D_; ++e) r += wo[o * 2 * D_ + e] * s_pool[e];
  #pragma unroll
  for (int e = 0; e < D_; ++e) r += wo[o * 2 * D_ + D_ + e] * emb[s * D_ + e];
  out[((size_t)b * S_ + rank) * D_ + o] = r;
}

extern "C" void kernel_launch(void* const* d_in, const int* in_sizes, int n_in,
                              void* d_out, int out_size, void* d_ws, size_t ws_size,
                              hipStream_t stream) {
  const int*   labels = (const int*)  d_in[0];
  const float* feat   = (const float*)d_in[1];
  const float* w1     = (const float*)d_in[2];
  const float* b1     = (const float*)d_in[3];
  const float* w2     = (const float*)d_in[4];
  const float* b2     = (const float*)d_in[5];
  const float* emb    = (const float*)d_in[6];
  const float* wo     = (const float*)d_in[7];
  const float* bo     = (const float*)d_in[8];
  float* out = (float*)d_out;

  // ws layout: gsum | gcnt | wbf
  char* w = (char*)d_ws;
  float* gsum = (float*)w;   w += (size_t)B_ * S_ * D_ * 4;
  int*   gcnt = (int*)w;     w += (size_t)B_ * S_ * 4;
  short* wbf  = (short*)w;

  hipMemsetAsync(d_ws, 0, (size_t)B_ * S_ * D_ * 4 + (size_t)B_ * S_ * 4, stream);
  hipMemsetAsync(d_out, 0, (size_t)out_size * sizeof(float), stream);

  w1_to_bf16<<<(C_ * D_ + 255) / 256, 256, 0, stream>>>(w1, wbf);

  dim3 grid(P_ / TMB, B_);
  proj_mfma<<<grid, 256, 0, stream>>>(labels, feat, wbf, b1, gsum, gcnt);
  seg_finalize2<<<dim3(S_, B_), 64, 0, stream>>>(gsum, gcnt, w2, b2, emb, wo, bo, out);
}